// Round 12
// baseline (218.837 us; speedup 1.0000x reference)
//
#include <hip/hip_runtime.h>
#include <hip/hip_bf16.h>

typedef int   i32x4  __attribute__((ext_vector_type(4)));
typedef int   i32x8  __attribute__((ext_vector_type(8)));
typedef float f32x16 __attribute__((ext_vector_type(16)));

__device__ inline void gload_lds16(const void* g, void* l) {
  __builtin_amdgcn_global_load_lds((const __attribute__((address_space(1))) void*)g,
                                   (__attribute__((address_space(3))) void*)l, 16, 0, 0);
}
__device__ inline void gload_lds4(const void* g, void* l) {
  __builtin_amdgcn_global_load_lds((const __attribute__((address_space(1))) void*)g,
                                   (__attribute__((address_space(3))) void*)l, 4, 0, 0);
}
__device__ inline i32x8 pad8(i32x4 v) {
  i32x8 r;
  r[0] = v[0]; r[1] = v[1]; r[2] = v[2]; r[3] = v[3];
  r[4] = 0; r[5] = 0; r[6] = 0; r[7] = 0;
  return r;
}

// ------------- Fused quantization: Hadamard(32) rotate + MXFP4 pack (x and w in one grid) ---
__global__ __launch_bounds__(256) void quant_fused(const float* __restrict__ x,
                                                   const float* __restrict__ wt,
                                                   unsigned char* __restrict__ xq,
                                                   unsigned char* __restrict__ xsc,
                                                   unsigned char* __restrict__ wq,
                                                   unsigned char* __restrict__ wsc,
                                                   const float* __restrict__ ags,
                                                   const float* __restrict__ wgs,
                                                   int xg, int Mrows, int Nrows, int kg) {
  const int first = blockIdx.x * 256;
  const bool isX = first < xg;
  const float* in        = isX ? x   : wt;
  unsigned char* outq    = isX ? xq  : wq;
  unsigned char* outsc   = isX ? xsc : wsc;
  const float gs         = isX ? ags[0] : wgs[0];
  const int rows         = isX ? Mrows : Nrows;
  const int base         = isX ? first : first - xg;
  const int g = base + threadIdx.x;
  const int r = g / kg, j = g - r * kg;

  float t[32];
  const float4* p4 = (const float4*)(in + (size_t)g * 32);
#pragma unroll
  for (int i = 0; i < 8; ++i) {
    float4 v4 = p4[i];
    t[4 * i + 0] = v4.x; t[4 * i + 1] = v4.y;
    t[4 * i + 2] = v4.z; t[4 * i + 3] = v4.w;
  }
#pragma unroll
  for (int s = 0; s < 5; ++s) {
    const int hh = 1 << s;
#pragma unroll
    for (int i = 0; i < 32; ++i) {
      if ((i & hh) == 0) {
        float a = t[i], b = t[i + hh];
        t[i] = a + b;
        t[i + hh] = a - b;
      }
    }
  }

  const float c = 0.17677669529663687f;  // 32^-0.5
  float v[32];
  float am = 0.0f;
#pragma unroll
  for (int i = 0; i < 32; ++i) {
    float vi = (t[i] * c) * gs;
    v[i] = vi;
    am = fmaxf(am, fabsf(vi));
  }

  float a6 = am / 6.0f;
  int ex;
  float mant = frexpf(a6, &ex);
  int e = (mant == 0.5f) ? ex - 1 : ex;  // exact ceil(log2(a6))
  if (e < -127) e = -127;
  if (e > 127) e = 127;
  float inv_s = ldexpf(1.0f, -e);

  unsigned int dw[4] = {0u, 0u, 0u, 0u};
#pragma unroll
  for (int i = 0; i < 32; ++i) {
    float u = v[i] * inv_s;
    float au = fabsf(u);
    int idx = (au > 0.25f) + (au > 0.75f) + (au > 1.25f) + (au > 1.75f)
            + (au > 2.5f) + (au > 3.5f) + (au > 5.0f);
    int code = idx | ((u < 0.0f) ? 8 : 0);
    dw[i >> 3] |= (unsigned)code << ((i & 7) * 4);
  }
  i32x4 packed;
  packed[0] = (int)dw[0]; packed[1] = (int)dw[1];
  packed[2] = (int)dw[2]; packed[3] = (int)dw[3];
  *(i32x4*)(outq + (size_t)r * ((size_t)kg * 16) + (size_t)j * 16) = packed;

  // scale byte: layout [superstep s(256k)][row][8B], byte p = h*4 + kk for block j0 = 2*kk + h
  int s = j >> 3, j0 = j & 7;
  int p = ((j0 & 1) << 2) | (j0 >> 1);
  if (kg == 128) {
    __shared__ unsigned char sl[256];  // [16 steps][2 rows][8B]
    sl[(s << 4) | ((r & 1) << 3) | p] = (unsigned char)(e + 127);
    __syncthreads();
    if (threadIdx.x < 64) {
      int si = threadIdx.x >> 2, wd = threadIdx.x & 3;
      unsigned int vv = *(const unsigned int*)&sl[(si << 4) | (wd << 2)];
      size_t r0 = (size_t)(base / 128);
      *(unsigned int*)(outsc + ((size_t)si * rows + r0) * 8 + (wd << 2)) = vv;
    }
  } else {
    outsc[((size_t)s * rows + r) * 8 + p] = (unsigned char)(e + 127);
  }
}

// ---------------- 128x128 MX-FP4 GEMM, BK=128, 4 blocks/CU, 1 barrier/tile ----------
// 4 waves (2M x 2N). LDS 36KB: 2buf x (A 8K + B 8K) + superstep scale dbuf 4K.
// Per tile: {stage set(t+1) -> other buf (its readers retired before prev tile's MFMA,
// ENDP(prev) in between -> race-free); ds_read frags of buf[p] (compiler auto-lgkm
// before MFMA); 8 MFMA (opsel parity selects k-half of superstep scale word);
// vmcnt(0) (staged set landed); barrier}. Swizzle: LDS(row,c) holds global
// (row, c^(row&3)); reads at ((2kk+h)^(row&3))<<4 - bank-uniform for b128.

#define STAGE2(mb, kt, ldsOp) do {                                                   \
    const unsigned char* _s0 = (mb) + (size_t)((w << 4) + (l >> 2)) * KB2            \
                      + (size_t)(kt) * 64 + (size_t)csw * 16;                        \
    gload_lds16(_s0, (unsigned char*)(ldsOp) + (w << 10));                           \
    gload_lds16(_s0 + ((size_t)KB2 << 6), (unsigned char*)(ldsOp) + 4096 + (w << 10)); \
  } while (0)

#define STAGE_ASC(ss, sbuf) gload_lds4(AscG + ((size_t)(ss) * M + brow) * 8 + (tid << 2), \
                                       (unsigned char*)&asc[sbuf][0] + (w << 8))
#define STAGE_BSC(ss, sbuf) gload_lds4(BscG + ((size_t)(ss) * N + bcol) * 8 + (tid << 2), \
                                       (unsigned char*)&bsc[sbuf][0] + (w << 8))

#define STAGESET(kt, bf) do {                                                        \
    STAGE2(Bb, kt, &lds[bf][1][0]);                                                  \
    STAGE2(Ab, kt, &lds[bf][0][0]);                                                  \
  } while (0)

#define LOADB(bf, ssel) do {                                                         \
    const unsigned char* _bb = &lds[bf][1][0];                                       \
    _Pragma("unroll")                                                                \
    for (int nt = 0; nt < 2; ++nt) {                                                 \
      int row = wn * 64 + nt * 32 + (l & 31);                                        \
      int xr = row & 3;                                                              \
      _Pragma("unroll")                                                              \
      for (int kk = 0; kk < 2; ++kk)                                                 \
        bfr[nt][kk] = *(const i32x4*)(_bb + row * 64 + (((kk * 2 + h) ^ xr) << 4));  \
      sb[nt] = *(const int*)((const unsigned char*)&bsc[ssel][0] + row * 8 + h * 4); \
    } } while (0)

#define LOADA(bf, ssel) do {                                                         \
    const unsigned char* _ab = &lds[bf][0][0];                                       \
    _Pragma("unroll")                                                                \
    for (int mt = 0; mt < 2; ++mt) {                                                 \
      int row = wm * 64 + mt * 32 + (l & 31);                                        \
      int xr = row & 3;                                                              \
      _Pragma("unroll")                                                              \
      for (int kk = 0; kk < 2; ++kk)                                                 \
        af[mt][kk] = *(const i32x4*)(_ab + row * 64 + (((kk * 2 + h) ^ xr) << 4));   \
      sa[mt] = *(const int*)((const unsigned char*)&asc[ssel][0] + row * 8 + h * 4); \
    } } while (0)

#define MF1(mt, nt, kk, OP)                                                          \
  acc[mt][nt] = __builtin_amdgcn_mfma_scale_f32_32x32x64_f8f6f4(                     \
      pad8(af[mt][kk]), pad8(bfr[nt][kk]), acc[mt][nt], 4, 4, OP, sa[mt], OP, sb[nt]);

#define MFMAQ8(P) do {                                                               \
    __builtin_amdgcn_s_setprio(1);                                                   \
    MF1(0, 0, 0, P) MF1(0, 1, 0, P) MF1(1, 0, 0, P) MF1(1, 1, 0, P)                  \
    MF1(0, 0, 1, P + 1) MF1(0, 1, 1, P + 1) MF1(1, 0, 1, P + 1) MF1(1, 1, 1, P + 1)  \
    __builtin_amdgcn_s_setprio(0);                                                   \
  } while (0)

#define VM0()  asm volatile("s_waitcnt vmcnt(0)" ::: "memory")
#define ENDP() __builtin_amdgcn_s_barrier()

__global__ __launch_bounds__(256, 4) void gemm128_fp4(const unsigned char* __restrict__ Aq,
                                                      const unsigned char* __restrict__ Bq,
                                                      const unsigned char* __restrict__ AscG,
                                                      const unsigned char* __restrict__ BscG,
                                                      float* __restrict__ C,
                                                      const float* __restrict__ bias,
                                                      const float* __restrict__ gsx,
                                                      const float* __restrict__ gsw,
                                                      int M, int N, int K) {
  __shared__ __align__(16) unsigned char lds[2][2][8192];  // [buf][A/B][128 rows x 64B]
  __shared__ __align__(16) unsigned char asc[2][1024];     // [sbuf][128 rows x 8B] per 256-k step
  __shared__ __align__(16) unsigned char bsc[2][1024];

  const int tid = threadIdx.x;
  const int w = tid >> 6, l = tid & 63;
  const int wm = w >> 1, wn = w & 1;
  const int h = l >> 5;
  const int csw = (l & 3) ^ ((l >> 2) & 3);  // inverse-swizzled source chunk
  const int KB2 = K >> 1;                    // bytes per row

  // T1 + L2 supertiling (proven: FETCH 148->70MB): XCD band + 8x8 supertiles.
  const int ntn = N >> 7;
  const int nwg = gridDim.x;
  int r_t, c_t;
  {
    int bid = blockIdx.x;
    if ((nwg & 7) == 0) {
      int x = bid & 7, o = bid >> 3, cpx = nwg >> 3;
      int rpx = cpx / ntn;
      if ((ntn & 7) == 0 && rpx > 0 && (cpx % ntn) == 0) {
        int g8 = o & 7, rr = (o >> 3) % rpx, ss = o / (8 * rpx);
        r_t = x * rpx + rr;
        c_t = ss * 8 + g8;
      } else {
        int lin = x * cpx + o;
        r_t = lin / ntn; c_t = lin % ntn;
      }
    } else {
      r_t = bid / ntn; c_t = bid % ntn;
    }
  }
  const size_t brow = (size_t)r_t * 128;
  const size_t bcol = (size_t)c_t * 128;

  const unsigned char* Ab = Aq + brow * (size_t)KB2;
  const unsigned char* Bb = Bq + bcol * (size_t)KB2;

  f32x16 acc[2][2];
#pragma unroll
  for (int m = 0; m < 2; ++m)
#pragma unroll
    for (int n = 0; n < 2; ++n)
#pragma unroll
      for (int r = 0; r < 16; ++r) acc[m][n][r] = 0.0f;

  i32x4 af[2][2], bfr[2][2];
  int sa[2], sb[2];

  const int nkt = K / 128;       // 32 tiles
  const int nss = K / 256;       // 16 scale supersteps

  // Prologue: set(0)->buf0 + scales(ss0); drain; barrier.
  STAGESET(0, 0);
  STAGE_BSC(0, 0); STAGE_ASC(0, 0);
  VM0();
  __builtin_amdgcn_s_barrier();

  for (int s = 0; s < nkt / 2; ++s) {
    const int t = 2 * s;
    const int t1 = t + 1;                            // < nkt (nkt even)
    const int t2 = (t + 2 < nkt) ? t + 2 : nkt - 1;  // tail: stages a buffer never read again
    const int ssel = s & 1;
    const int ss1 = (s + 1 < nss) ? s + 1 : nss - 1;

    // even tile t: reads buf0 + sbuf[ssel]; stages set(t+1)->buf1 (readers retired
    // before tile t-1's MFMA, ENDP(t-1) in between) + next-superstep scales.
    STAGESET(t1, 1);
    STAGE_BSC(ss1, ssel ^ 1); STAGE_ASC(ss1, ssel ^ 1);
    LOADB(0, ssel); LOADA(0, ssel);
    MFMAQ8(0);                   // auto-lgkm waits cover the ds_reads
    VM0();                       // set(t+1)+scales landed
    ENDP();

    // odd tile t+1: reads buf1 + sbuf[ssel]; stages set(t+2)->buf0 (buf0 readers
    // retired before even tile's MFMA, ENDP(t) in between).
    STAGESET(t2, 0);
    LOADB(1, ssel); LOADA(1, ssel);
    MFMAQ8(2);
    VM0();
    ENDP();
  }

  const float inv = 1.0f / (gsx[0] * gsw[0]);
#pragma unroll
  for (int nt = 0; nt < 2; ++nt) {
    const int col = (int)bcol + wn * 64 + nt * 32 + (l & 31);
    const float bv = bias[col];
#pragma unroll
    for (int mt = 0; mt < 2; ++mt) {
      const size_t rbase = brow + (size_t)(wm * 64 + mt * 32 + 4 * h);
#pragma unroll
      for (int r = 0; r < 16; ++r) {
        const size_t row = rbase + (r & 3) + 8 * (r >> 2);
        C[row * (size_t)N + col] = acc[mt][nt][r] * inv + bv;
      }
    }
  }
}

extern "C" void kernel_launch(void* const* d_in, const int* in_sizes, int n_in,
                              void* d_out, int out_size, void* d_ws, size_t ws_size,
                              hipStream_t stream) {
  const float* x    = (const float*)d_in[0];
  const float* wgt  = (const float*)d_in[1];
  const float* bias = (const float*)d_in[2];
  const float* wgs  = (const float*)d_in[4];
  const float* ags  = (const float*)d_in[5];

  const int N = in_sizes[2];            // 4096
  const int K = in_sizes[1] / N;        // 4096
  const int M = in_sizes[0] / K;        // 8192
  const int kg = K / 32;                // 128

  unsigned char* aq  = (unsigned char*)d_ws;
  unsigned char* bq  = aq + (size_t)M * (K / 2);
  unsigned char* asc = bq + (size_t)N * (K / 2);
  unsigned char* bsc = asc + (size_t)M * kg;

  const int xg = in_sizes[0] / 32;
  const int wg = in_sizes[1] / 32;
  quant_fused<<<dim3((xg + wg) / 256), dim3(256), 0, stream>>>(
      x, wgt, aq, asc, bq, bsc, ags, wgs, xg, M, N, kg);

  dim3 grid((M / 128) * (N / 128));
  gemm128_fp4<<<grid, dim3(256), 0, stream>>>(aq, bq, asc, bsc, (float*)d_out, bias,
                                              ags, wgs, M, N, K);
}

// Round 13
// 154.995 us; speedup vs baseline: 1.4119x; 1.4119x over previous
//
#include <hip/hip_runtime.h>
#include <hip/hip_bf16.h>

typedef int   i32x4  __attribute__((ext_vector_type(4)));
typedef int   i32x8  __attribute__((ext_vector_type(8)));
typedef float f32x16 __attribute__((ext_vector_type(16)));

__device__ inline void gload_lds16(const void* g, void* l) {
  __builtin_amdgcn_global_load_lds((const __attribute__((address_space(1))) void*)g,
                                   (__attribute__((address_space(3))) void*)l, 16, 0, 0);
}
__device__ inline void gload_lds4(const void* g, void* l) {
  __builtin_amdgcn_global_load_lds((const __attribute__((address_space(1))) void*)g,
                                   (__attribute__((address_space(3))) void*)l, 4, 0, 0);
}
__device__ inline i32x8 pad8(i32x4 v) {
  i32x8 r;
  r[0] = v[0]; r[1] = v[1]; r[2] = v[2]; r[3] = v[3];
  r[4] = 0; r[5] = 0; r[6] = 0; r[7] = 0;
  return r;
}

// ------------- Fused quantization: Hadamard(32) rotate + MXFP4 pack (x and w in one grid) ---
__global__ __launch_bounds__(256) void quant_fused(const float* __restrict__ x,
                                                   const float* __restrict__ wt,
                                                   unsigned char* __restrict__ xq,
                                                   unsigned char* __restrict__ xsc,
                                                   unsigned char* __restrict__ wq,
                                                   unsigned char* __restrict__ wsc,
                                                   const float* __restrict__ ags,
                                                   const float* __restrict__ wgs,
                                                   int xg, int Mrows, int Nrows, int kg) {
  const int first = blockIdx.x * 256;
  const bool isX = first < xg;
  const float* in        = isX ? x   : wt;
  unsigned char* outq    = isX ? xq  : wq;
  unsigned char* outsc   = isX ? xsc : wsc;
  const float gs         = isX ? ags[0] : wgs[0];
  const int rows         = isX ? Mrows : Nrows;
  const int base         = isX ? first : first - xg;
  const int g = base + threadIdx.x;
  const int r = g / kg, j = g - r * kg;

  float t[32];
  const float4* p4 = (const float4*)(in + (size_t)g * 32);
#pragma unroll
  for (int i = 0; i < 8; ++i) {
    float4 v4 = p4[i];
    t[4 * i + 0] = v4.x; t[4 * i + 1] = v4.y;
    t[4 * i + 2] = v4.z; t[4 * i + 3] = v4.w;
  }
#pragma unroll
  for (int s = 0; s < 5; ++s) {
    const int hh = 1 << s;
#pragma unroll
    for (int i = 0; i < 32; ++i) {
      if ((i & hh) == 0) {
        float a = t[i], b = t[i + hh];
        t[i] = a + b;
        t[i + hh] = a - b;
      }
    }
  }

  const float c = 0.17677669529663687f;  // 32^-0.5
  float v[32];
  float am = 0.0f;
#pragma unroll
  for (int i = 0; i < 32; ++i) {
    float vi = (t[i] * c) * gs;
    v[i] = vi;
    am = fmaxf(am, fabsf(vi));
  }

  float a6 = am / 6.0f;
  int ex;
  float mant = frexpf(a6, &ex);
  int e = (mant == 0.5f) ? ex - 1 : ex;  // exact ceil(log2(a6))
  if (e < -127) e = -127;
  if (e > 127) e = 127;
  float inv_s = ldexpf(1.0f, -e);

  unsigned int dw[4] = {0u, 0u, 0u, 0u};
#pragma unroll
  for (int i = 0; i < 32; ++i) {
    float u = v[i] * inv_s;
    float au = fabsf(u);
    int idx = (au > 0.25f) + (au > 0.75f) + (au > 1.25f) + (au > 1.75f)
            + (au > 2.5f) + (au > 3.5f) + (au > 5.0f);
    int code = idx | ((u < 0.0f) ? 8 : 0);
    dw[i >> 3] |= (unsigned)code << ((i & 7) * 4);
  }
  i32x4 packed;
  packed[0] = (int)dw[0]; packed[1] = (int)dw[1];
  packed[2] = (int)dw[2]; packed[3] = (int)dw[3];
  *(i32x4*)(outq + (size_t)r * ((size_t)kg * 16) + (size_t)j * 16) = packed;

  // scale byte: layout [superstep s(256k)][row][8B], byte p = h*4 + kk for block j0 = 2*kk + h
  int s = j >> 3, j0 = j & 7;
  int p = ((j0 & 1) << 2) | (j0 >> 1);
  if (kg == 128) {
    __shared__ unsigned char sl[256];  // [16 steps][2 rows][8B]
    sl[(s << 4) | ((r & 1) << 3) | p] = (unsigned char)(e + 127);
    __syncthreads();
    if (threadIdx.x < 64) {
      int si = threadIdx.x >> 2, wd = threadIdx.x & 3;
      unsigned int vv = *(const unsigned int*)&sl[(si << 4) | (wd << 2)];
      size_t r0 = (size_t)(base / 128);
      *(unsigned int*)(outsc + ((size_t)si * rows + r0) * 8 + (wd << 2)) = vv;
    }
  } else {
    outsc[((size_t)s * rows + r) * 8 + p] = (unsigned char)(e + 127);
  }
}

// ---------------- 128x128 MX-FP4 GEMM, BK=256, 512 threads (8 waves of 64x32) ----------
// R11's race-free one-phase skeleton; acc/wave = 32 regs so 4 waves/SIMD fit under the
// 128-reg unified cap (R12's spill mechanism avoided by design). Per tile:
// {12 ds_read_b128 + 3 b32 -> lgkmcnt(0) -> barrier -> stage set(t+2) into just-read
// buf -> 8 MFMA -> vmcnt(5) -> barrier}. Ledger: 5 VMEM/set (2B+2A+1 scale per wave;
// waves 0-3 stage A-scales, 4-7 B-scales -> per-wave vmcnt uniform).

#define STAGE1(mb, kt, hh, ldsAB) do {                                               \
    const unsigned char* _s = (mb) + (size_t)((hh)*64 + (w << 3) + (l >> 3)) * KB2   \
                      + (size_t)(kt) * 128 + (size_t)csw * 16;                       \
    gload_lds16(_s, (unsigned char*)(ldsAB) + (hh) * 8192 + (w << 10));              \
  } while (0)

// per-wave: 2 B-gloads + 2 A-gloads + 1 scale gload = 5 VMEM
#define STAGESET(kt, bf) do {                                                        \
    STAGE1(Bb, kt, 0, &lds[bf][1][0]); STAGE1(Bb, kt, 1, &lds[bf][1][0]);            \
    STAGE1(Ab, kt, 0, &lds[bf][0][0]); STAGE1(Ab, kt, 1, &lds[bf][0][0]);            \
    if (w < 4)                                                                       \
      gload_lds4(AscG + ((size_t)(kt) * M + brow) * 8 + ((tid & 255) << 2),          \
                 (unsigned char*)&asc[bf][0] + ((w & 3) << 8));                      \
    else                                                                             \
      gload_lds4(BscG + ((size_t)(kt) * N + bcol) * 8 + ((tid & 255) << 2),          \
                 (unsigned char*)&bsc[bf][0] + ((w & 3) << 8));                      \
  } while (0)

#define LOADB(bf) do {                                                               \
    const unsigned char* _bb = &lds[bf][1][0];                                       \
    int row = wn * 32 + (l & 31);                                                    \
    int xr = row & 7;                                                                \
    _Pragma("unroll")                                                                \
    for (int kk = 0; kk < 4; ++kk)                                                   \
      bfr[kk] = *(const i32x4*)(_bb + row * 128 + (((kk * 2 + h) ^ xr) << 4));       \
    sb = *(const int*)((const unsigned char*)&bsc[bf][0] + row * 8 + h * 4);         \
  } while (0)

#define LOADA(bf) do {                                                               \
    const unsigned char* _ab = &lds[bf][0][0];                                       \
    _Pragma("unroll")                                                                \
    for (int mt = 0; mt < 2; ++mt) {                                                 \
      int row = wm * 64 + mt * 32 + (l & 31);                                        \
      int xr = row & 7;                                                              \
      _Pragma("unroll")                                                              \
      for (int kk = 0; kk < 4; ++kk)                                                 \
        af[mt][kk] = *(const i32x4*)(_ab + row * 128 + (((kk * 2 + h) ^ xr) << 4));  \
      sa[mt] = *(const int*)((const unsigned char*)&asc[bf][0] + row * 8 + h * 4);   \
    } } while (0)

#define MF1(mt, kk)                                                                  \
  acc[mt] = __builtin_amdgcn_mfma_scale_f32_32x32x64_f8f6f4(                         \
      pad8(af[mt][kk]), pad8(bfr[kk]), acc[mt], 4, 4, kk, sa[mt], kk, sb);

#define MFMAQ8() do {                                                                \
    __builtin_amdgcn_s_setprio(1);                                                   \
    MF1(0, 0) MF1(1, 0) MF1(0, 1) MF1(1, 1)                                          \
    MF1(0, 2) MF1(1, 2) MF1(0, 3) MF1(1, 3)                                          \
    __builtin_amdgcn_s_setprio(0);                                                   \
  } while (0)

#define DRAIN_THEN_BAR() do {                                                        \
    asm volatile("s_waitcnt lgkmcnt(0)" ::: "memory");                               \
    __builtin_amdgcn_sched_barrier(0);                                               \
    __builtin_amdgcn_s_barrier();                                                    \
  } while (0)

#define ENDP() __builtin_amdgcn_s_barrier()
#define VM5()  asm volatile("s_waitcnt vmcnt(5)" ::: "memory")

__global__ __launch_bounds__(512, 4) void gemm128_fp4(const unsigned char* __restrict__ Aq,
                                                      const unsigned char* __restrict__ Bq,
                                                      const unsigned char* __restrict__ AscG,
                                                      const unsigned char* __restrict__ BscG,
                                                      float* __restrict__ C,
                                                      const float* __restrict__ bias,
                                                      const float* __restrict__ gsx,
                                                      const float* __restrict__ gsw,
                                                      int M, int N, int K) {
  __shared__ __align__(16) unsigned char lds[2][2][16384];  // [buf][A/B][128 rows x 128B]
  __shared__ __align__(16) unsigned char asc[2][1024];      // [buf][128 rows x 8B]
  __shared__ __align__(16) unsigned char bsc[2][1024];

  const int tid = threadIdx.x;
  const int w = tid >> 6, l = tid & 63;
  const int wm = w >> 2, wn = w & 3;   // 2M x 4N waves, each 64x32 output
  const int h = l >> 5;
  const int csw = (l & 7) ^ (l >> 3);  // inverse-swizzled source chunk (row&7 == l>>3)
  const int KB2 = K >> 1;              // bytes per row

  // T1 + L2 supertiling (proven: FETCH 148->70MB): XCD band + 8x8 supertiles.
  const int ntn = N >> 7;
  const int nwg = gridDim.x;
  int r_t, c_t;
  {
    int bid = blockIdx.x;
    if ((nwg & 7) == 0) {
      int x = bid & 7, o = bid >> 3, cpx = nwg >> 3;
      int rpx = cpx / ntn;
      if ((ntn & 7) == 0 && rpx > 0 && (cpx % ntn) == 0) {
        int g8 = o & 7, rr = (o >> 3) % rpx, ss = o / (8 * rpx);
        r_t = x * rpx + rr;
        c_t = ss * 8 + g8;
      } else {
        int lin = x * cpx + o;
        r_t = lin / ntn; c_t = lin % ntn;
      }
    } else {
      r_t = bid / ntn; c_t = bid % ntn;
    }
  }
  const size_t brow = (size_t)r_t * 128;
  const size_t bcol = (size_t)c_t * 128;

  const unsigned char* Ab = Aq + brow * (size_t)KB2;
  const unsigned char* Bb = Bq + bcol * (size_t)KB2;

  f32x16 acc[2];
#pragma unroll
  for (int m = 0; m < 2; ++m)
#pragma unroll
    for (int r = 0; r < 16; ++r) acc[m][r] = 0.0f;

  i32x4 af[2][4], bfr[4];
  int sa[2], sb;

  const int nkt = K / 256;       // 16 tiles; scale step index == tile index

  // Prologue: set(0)->buf0 (5/wave), set(1)->buf1 (5/wave); VM5 drains set0.
  STAGESET(0, 0);
  STAGESET(1, 1);
  VM5();
  __builtin_amdgcn_s_barrier();

  for (int t = 0; t < nkt; ++t) {
    const int p = t & 1;
    const int t2 = (t + 2 < nkt) ? t + 2 : nkt - 1;  // tail: stages a buffer never read again

    LOADB(p); LOADA(p);          // 12 ds_read_b128 + 3 b32 into regs
    DRAIN_THEN_BAR();            // all waves' reads of buf[p] complete before anyone stages
    STAGESET(t2, p);             // overwrite buf[p] (readers provably done)
    __builtin_amdgcn_sched_barrier(0);
    MFMAQ8();                    // compute on registers while DMA flies
    VM5();                       // drains set(t+1); keeps set(t+2) in flight
    ENDP();
  }

  const float inv = 1.0f / (gsx[0] * gsw[0]);
  {
    const int col = (int)bcol + wn * 32 + (l & 31);
    const float bv = bias[col];
#pragma unroll
    for (int mt = 0; mt < 2; ++mt) {
      const size_t rbase = brow + (size_t)(wm * 64 + mt * 32 + 4 * h);
#pragma unroll
      for (int r = 0; r < 16; ++r) {
        const size_t row = rbase + (r & 3) + 8 * (r >> 2);
        C[row * (size_t)N + col] = acc[mt][r] * inv + bv;
      }
    }
  }
}

extern "C" void kernel_launch(void* const* d_in, const int* in_sizes, int n_in,
                              void* d_out, int out_size, void* d_ws, size_t ws_size,
                              hipStream_t stream) {
  const float* x    = (const float*)d_in[0];
  const float* wgt  = (const float*)d_in[1];
  const float* bias = (const float*)d_in[2];
  const float* wgs  = (const float*)d_in[4];
  const float* ags  = (const float*)d_in[5];

  const int N = in_sizes[2];            // 4096
  const int K = in_sizes[1] / N;        // 4096
  const int M = in_sizes[0] / K;        // 8192
  const int kg = K / 32;                // 128

  unsigned char* aq  = (unsigned char*)d_ws;
  unsigned char* bq  = aq + (size_t)M * (K / 2);
  unsigned char* asc = bq + (size_t)N * (K / 2);
  unsigned char* bsc = asc + (size_t)M * kg;

  const int xg = in_sizes[0] / 32;
  const int wg = in_sizes[1] / 32;
  quant_fused<<<dim3((xg + wg) / 256), dim3(256), 0, stream>>>(
      x, wgt, aq, asc, bq, bsc, ags, wgs, xg, M, N, kg);

  dim3 grid((M / 128) * (N / 128));
  gemm128_fp4<<<grid, dim3(512), 0, stream>>>(aq, bq, asc, bsc, (float*)d_out, bias,
                                              ags, wgs, M, N, K);
}

// Round 14
// 150.644 us; speedup vs baseline: 1.4527x; 1.0289x over previous
//
#include <hip/hip_runtime.h>
#include <hip/hip_bf16.h>

typedef int   i32x4  __attribute__((ext_vector_type(4)));
typedef int   i32x8  __attribute__((ext_vector_type(8)));
typedef float f32x16 __attribute__((ext_vector_type(16)));

__device__ inline void gload_lds16(const void* g, void* l) {
  __builtin_amdgcn_global_load_lds((const __attribute__((address_space(1))) void*)g,
                                   (__attribute__((address_space(3))) void*)l, 16, 0, 0);
}
__device__ inline void gload_lds4(const void* g, void* l) {
  __builtin_amdgcn_global_load_lds((const __attribute__((address_space(1))) void*)g,
                                   (__attribute__((address_space(3))) void*)l, 4, 0, 0);
}

// ------------- Fused quantization: Hadamard(32) rotate + MXFP4 pack (x and w in one grid) ---
// At HBM roofline (~228MB moved, ~34us observed vs 36us floor) - unchanged.
__global__ __launch_bounds__(256) void quant_fused(const float* __restrict__ x,
                                                   const float* __restrict__ wt,
                                                   unsigned char* __restrict__ xq,
                                                   unsigned char* __restrict__ xsc,
                                                   unsigned char* __restrict__ wq,
                                                   unsigned char* __restrict__ wsc,
                                                   const float* __restrict__ ags,
                                                   const float* __restrict__ wgs,
                                                   int xg, int Mrows, int Nrows, int kg) {
  const int first = blockIdx.x * 256;
  const bool isX = first < xg;
  const float* in        = isX ? x   : wt;
  unsigned char* outq    = isX ? xq  : wq;
  unsigned char* outsc   = isX ? xsc : wsc;
  const float gs         = isX ? ags[0] : wgs[0];
  const int rows         = isX ? Mrows : Nrows;
  const int base         = isX ? first : first - xg;
  const int g = base + threadIdx.x;
  const int r = g / kg, j = g - r * kg;

  float t[32];
  const float4* p4 = (const float4*)(in + (size_t)g * 32);
#pragma unroll
  for (int i = 0; i < 8; ++i) {
    float4 v4 = p4[i];
    t[4 * i + 0] = v4.x; t[4 * i + 1] = v4.y;
    t[4 * i + 2] = v4.z; t[4 * i + 3] = v4.w;
  }
#pragma unroll
  for (int s = 0; s < 5; ++s) {
    const int hh = 1 << s;
#pragma unroll
    for (int i = 0; i < 32; ++i) {
      if ((i & hh) == 0) {
        float a = t[i], b = t[i + hh];
        t[i] = a + b;
        t[i + hh] = a - b;
      }
    }
  }

  const float c = 0.17677669529663687f;  // 32^-0.5
  float v[32];
  float am = 0.0f;
#pragma unroll
  for (int i = 0; i < 32; ++i) {
    float vi = (t[i] * c) * gs;
    v[i] = vi;
    am = fmaxf(am, fabsf(vi));
  }

  float a6 = am / 6.0f;
  int ex;
  float mant = frexpf(a6, &ex);
  int e = (mant == 0.5f) ? ex - 1 : ex;  // exact ceil(log2(a6))
  if (e < -127) e = -127;
  if (e > 127) e = 127;
  float inv_s = ldexpf(1.0f, -e);

  unsigned int dw[4] = {0u, 0u, 0u, 0u};
#pragma unroll
  for (int i = 0; i < 32; ++i) {
    float u = v[i] * inv_s;
    float au = fabsf(u);
    int idx = (au > 0.25f) + (au > 0.75f) + (au > 1.25f) + (au > 1.75f)
            + (au > 2.5f) + (au > 3.5f) + (au > 5.0f);
    int code = idx | ((u < 0.0f) ? 8 : 0);
    dw[i >> 3] |= (unsigned)code << ((i & 7) * 4);
  }
  i32x4 packed;
  packed[0] = (int)dw[0]; packed[1] = (int)dw[1];
  packed[2] = (int)dw[2]; packed[3] = (int)dw[3];
  *(i32x4*)(outq + (size_t)r * ((size_t)kg * 16) + (size_t)j * 16) = packed;

  // scale byte: layout [step s(256k)][row][8B], byte p = h*4 + kk for block j0 = 2*kk + h
  int s = j >> 3, j0 = j & 7;
  int p = ((j0 & 1) << 2) | (j0 >> 1);
  if (kg == 128) {
    __shared__ unsigned char sl[256];  // [16 steps][2 rows][8B]
    sl[(s << 4) | ((r & 1) << 3) | p] = (unsigned char)(e + 127);
    __syncthreads();
    if (threadIdx.x < 64) {
      int si = threadIdx.x >> 2, wd = threadIdx.x & 3;
      unsigned int vv = *(const unsigned int*)&sl[(si << 4) | (wd << 2)];
      size_t r0 = (size_t)(base / 128);
      *(unsigned int*)(outsc + ((size_t)si * rows + r0) * 8 + (wd << 2)) = vv;
    }
  } else {
    outsc[((size_t)s * rows + r) * 8 + p] = (unsigned char)(e + 127);
  }
}

// ---------------- 128x128 MX-FP4 GEMM, BK=256, R11 skeleton + i32x8 frags + rotated reads --
// 4 waves (2M x 2N of 64x64), 2 blocks/CU. Per tile:
// {lgkmcnt(0) [drains reads issued at end of prev tile] -> barrier [all waves' reads of
// buf[p] done] -> stage set(t+2) -> buf[p] -> 16 MFMA (frags already in regs, zero VALU:
// persistent i32x8 tuples, fp4 MFMA reads only low 4 regs, hi zeroed once) ->
// vmcnt(10) [set(t+1) landed] -> barrier -> ds_read frags(t+1) from buf[p^1]}.
// Ledger: 10 VMEM/set; steady queue [set(t+1)^10, set(t+2)^10]; VM10 drains set(t+1).

#define STAGE(mb, kt, hh, ldsHalf) do {                                              \
    const unsigned char* _s = (mb) + (size_t)((hh)*64 + (w << 3) + (l >> 3)) * KB2   \
                      + (size_t)(kt) * 128 + (size_t)csw * 16;                       \
    gload_lds16(_s, (unsigned char*)(ldsHalf) + (w << 10));                          \
    gload_lds16(_s + ((size_t)KB2 << 5), (unsigned char*)(ldsHalf) + (w << 10) + 4096); \
  } while (0)

#define STAGE_ASC(kt, bf) gload_lds4(AscG + ((size_t)(kt) * M + brow) * 8 + (tid << 2), \
                                     (unsigned char*)&asc[bf][0] + (w << 8))
#define STAGE_BSC(kt, bf) gload_lds4(BscG + ((size_t)(kt) * N + bcol) * 8 + (tid << 2), \
                                     (unsigned char*)&bsc[bf][0] + (w << 8))

// full tile set: 4 B-data + BSC + 4 A-data + ASC = 10 VMEM
#define STAGESET(kt, bf) do {                                                        \
    STAGE(Bb, kt, 0, &lds[bf][1][0]); STAGE(Bb, kt, 1, &lds[bf][1][8192]);           \
    STAGE_BSC(kt, bf);                                                               \
    STAGE(Ab, kt, 0, &lds[bf][0][0]); STAGE(Ab, kt, 1, &lds[bf][0][8192]);           \
    STAGE_ASC(kt, bf);                                                               \
  } while (0)

// reads land in the LOW half of persistent i32x8 tuples (hi stays zero)
#define READFRAGS(bf) do {                                                           \
    const unsigned char* _bb = &lds[bf][1][0];                                       \
    _Pragma("unroll")                                                                \
    for (int nt = 0; nt < 2; ++nt) {                                                 \
      int row = wn * 64 + nt * 32 + (l & 31);                                        \
      int xr = row & 7;                                                              \
      _Pragma("unroll")                                                              \
      for (int kk = 0; kk < 4; ++kk)                                                 \
        *(i32x4*)&bf8[nt][kk] = *(const i32x4*)(_bb + row * 128 + (((kk * 2 + h) ^ xr) << 4)); \
      sb[nt] = *(const int*)((const unsigned char*)&bsc[bf][0] + row * 8 + h * 4);   \
    }                                                                                \
    const unsigned char* _ab = &lds[bf][0][0];                                       \
    _Pragma("unroll")                                                                \
    for (int mt = 0; mt < 2; ++mt) {                                                 \
      int row = wm * 64 + mt * 32 + (l & 31);                                        \
      int xr = row & 7;                                                              \
      _Pragma("unroll")                                                              \
      for (int kk = 0; kk < 4; ++kk)                                                 \
        *(i32x4*)&af8[mt][kk] = *(const i32x4*)(_ab + row * 128 + (((kk * 2 + h) ^ xr) << 4)); \
      sa[mt] = *(const int*)((const unsigned char*)&asc[bf][0] + row * 8 + h * 4);   \
    } } while (0)

#define MF1(mt, nt, kk)                                                              \
  acc[mt][nt] = __builtin_amdgcn_mfma_scale_f32_32x32x64_f8f6f4(                     \
      af8[mt][kk], bf8[nt][kk], acc[mt][nt], 4, 4, kk, sa[mt], kk, sb[nt]);

#define MFMAQ16() do {                                                               \
    __builtin_amdgcn_s_setprio(1);                                                   \
    MF1(0, 0, 0) MF1(0, 1, 0) MF1(1, 0, 0) MF1(1, 1, 0)                              \
    MF1(0, 0, 1) MF1(0, 1, 1) MF1(1, 0, 1) MF1(1, 1, 1)                              \
    MF1(0, 0, 2) MF1(0, 1, 2) MF1(1, 0, 2) MF1(1, 1, 2)                              \
    MF1(0, 0, 3) MF1(0, 1, 3) MF1(1, 0, 3) MF1(1, 1, 3)                              \
    __builtin_amdgcn_s_setprio(0);                                                   \
  } while (0)

#define DRAIN_THEN_BAR() do {                                                        \
    asm volatile("s_waitcnt lgkmcnt(0)" ::: "memory");                               \
    __builtin_amdgcn_sched_barrier(0);                                               \
    __builtin_amdgcn_s_barrier();                                                    \
  } while (0)

#define ENDP() __builtin_amdgcn_s_barrier()
#define VM10() asm volatile("s_waitcnt vmcnt(10)" ::: "memory")

__global__ __launch_bounds__(256, 2) void gemm128_fp4(const unsigned char* __restrict__ Aq,
                                                      const unsigned char* __restrict__ Bq,
                                                      const unsigned char* __restrict__ AscG,
                                                      const unsigned char* __restrict__ BscG,
                                                      float* __restrict__ C,
                                                      const float* __restrict__ bias,
                                                      const float* __restrict__ gsx,
                                                      const float* __restrict__ gsw,
                                                      int M, int N, int K) {
  __shared__ __align__(16) unsigned char lds[2][2][16384];  // [buf][A/B][128 rows x 128B]
  __shared__ __align__(16) unsigned char asc[2][1024];      // [buf][128 rows x 8B]
  __shared__ __align__(16) unsigned char bsc[2][1024];

  const int tid = threadIdx.x;
  const int w = tid >> 6, l = tid & 63;
  const int wm = w >> 1, wn = w & 1;
  const int h = l >> 5;
  const int csw = (l & 7) ^ (l >> 3);  // inverse-swizzled source chunk (row&7 == l>>3)
  const int KB2 = K >> 1;              // bytes per row

  // T1 + L2 supertiling (proven: FETCH 148->70MB): XCD band + 8x8 supertiles.
  const int ntn = N >> 7;
  const int nwg = gridDim.x;
  int r_t, c_t;
  {
    int bid = blockIdx.x;
    if ((nwg & 7) == 0) {
      int x = bid & 7, o = bid >> 3, cpx = nwg >> 3;
      int rpx = cpx / ntn;
      if ((ntn & 7) == 0 && rpx > 0 && (cpx % ntn) == 0) {
        int g8 = o & 7, rr = (o >> 3) % rpx, ss = o / (8 * rpx);
        r_t = x * rpx + rr;
        c_t = ss * 8 + g8;
      } else {
        int lin = x * cpx + o;
        r_t = lin / ntn; c_t = lin % ntn;
      }
    } else {
      r_t = bid / ntn; c_t = bid % ntn;
    }
  }
  const size_t brow = (size_t)r_t * 128;
  const size_t bcol = (size_t)c_t * 128;

  const unsigned char* Ab = Aq + brow * (size_t)KB2;
  const unsigned char* Bb = Bq + bcol * (size_t)KB2;

  f32x16 acc[2][2];
#pragma unroll
  for (int m = 0; m < 2; ++m)
#pragma unroll
    for (int n = 0; n < 2; ++n)
#pragma unroll
      for (int r = 0; r < 16; ++r) acc[m][n][r] = 0.0f;

  // Persistent MFMA operand tuples: hi half zeroed ONCE (fp4 fmt reads only lo 4 regs,
  // but keep hi defined); lo half overwritten by ds_read each tile -> no pad copies.
  i32x8 af8[2][4], bf8[2][4];
#pragma unroll
  for (int mt = 0; mt < 2; ++mt)
#pragma unroll
    for (int kk = 0; kk < 4; ++kk) {
#pragma unroll
      for (int q = 0; q < 8; ++q) { af8[mt][kk][q] = 0; bf8[mt][kk][q] = 0; }
    }
  int sa[2], sb[2];

  const int nkt = K / 256;       // 16 tiles; scale step index == tile index

  // Prologue: set(0)->buf0 (10), set(1)->buf1 (10); VM10 drains set0; prime frags(0).
  STAGESET(0, 0);
  STAGESET(1, 1);
  VM10();
  __builtin_amdgcn_s_barrier();
  READFRAGS(0);

  for (int t = 0; t < nkt; ++t) {
    const int p = t & 1;
    const int t2 = (t + 2 < nkt) ? t + 2 : nkt - 1;  // tail: stages a buffer never read again

    DRAIN_THEN_BAR();            // drain reads issued at end of prev iter; all waves done
    STAGESET(t2, p);             // overwrite buf[p] (readers provably done)
    __builtin_amdgcn_sched_barrier(0);
    MFMAQ16();                   // frags(t) already resident; zero operand-copy VALU
    VM10();                      // set(t+1) landed
    ENDP();
    READFRAGS(p ^ 1);            // issue reads of frags(t+1); drained at next iter top
                                 // (t = nkt-1: dead read of stale buf, values unused)
  }

  const float inv = 1.0f / (gsx[0] * gsw[0]);
#pragma unroll
  for (int nt = 0; nt < 2; ++nt) {
    const int col = (int)bcol + wn * 64 + nt * 32 + (l & 31);
    const float bv = bias[col];
#pragma unroll
    for (int mt = 0; mt < 2; ++mt) {
      const size_t rbase = brow + (size_t)(wm * 64 + mt * 32 + 4 * h);
#pragma unroll
      for (int r = 0; r < 16; ++r) {
        const size_t row = rbase + (r & 3) + 8 * (r >> 2);
        C[row * (size_t)N + col] = acc[mt][nt][r] * inv + bv;
      }
    }
  }
}

extern "C" void kernel_launch(void* const* d_in, const int* in_sizes, int n_in,
                              void* d_out, int out_size, void* d_ws, size_t ws_size,
                              hipStream_t stream) {
  const float* x    = (const float*)d_in[0];
  const float* wgt  = (const float*)d_in[1];
  const float* bias = (const float*)d_in[2];
  const float* wgs  = (const float*)d_in[4];
  const float* ags  = (const float*)d_in[5];

  const int N = in_sizes[2];            // 4096
  const int K = in_sizes[1] / N;        // 4096
  const int M = in_sizes[0] / K;        // 8192
  const int kg = K / 32;                // 128

  unsigned char* aq  = (unsigned char*)d_ws;
  unsigned char* bq  = aq + (size_t)M * (K / 2);
  unsigned char* asc = bq + (size_t)N * (K / 2);
  unsigned char* bsc = asc + (size_t)M * kg;

  const int xg = in_sizes[0] / 32;
  const int wg = in_sizes[1] / 32;
  quant_fused<<<dim3((xg + wg) / 256), dim3(256), 0, stream>>>(
      x, wgt, aq, asc, bq, bsc, ags, wgs, xg, M, N, kg);

  dim3 grid((M / 128) * (N / 128));
  gemm128_fp4<<<grid, dim3(256), 0, stream>>>(aq, bq, asc, bsc, (float*)d_out, bias,
                                              ags, wgs, M, N, K);
}

// Round 16
// 149.449 us; speedup vs baseline: 1.4643x; 1.0080x over previous
//
#include <hip/hip_runtime.h>
#include <hip/hip_bf16.h>

typedef int   i32x4  __attribute__((ext_vector_type(4)));
typedef int   i32x8  __attribute__((ext_vector_type(8)));
typedef float f32x16 __attribute__((ext_vector_type(16)));

__device__ inline void gload_lds16(const void* g, void* l) {
  __builtin_amdgcn_global_load_lds((const __attribute__((address_space(1))) void*)g,
                                   (__attribute__((address_space(3))) void*)l, 16, 0, 0);
}
__device__ inline void gload_lds4(const void* g, void* l) {
  __builtin_amdgcn_global_load_lds((const __attribute__((address_space(1))) void*)g,
                                   (__attribute__((address_space(3))) void*)l, 4, 0, 0);
}

// ------------- Fused quantization: Hadamard(32) rotate + MXFP4 pack (x and w in one grid) ---
// At HBM roofline (~228MB moved vs ~36us floor) - unchanged since R7.
__global__ __launch_bounds__(256) void quant_fused(const float* __restrict__ x,
                                                   const float* __restrict__ wt,
                                                   unsigned char* __restrict__ xq,
                                                   unsigned char* __restrict__ xsc,
                                                   unsigned char* __restrict__ wq,
                                                   unsigned char* __restrict__ wsc,
                                                   const float* __restrict__ ags,
                                                   const float* __restrict__ wgs,
                                                   int xg, int Mrows, int Nrows, int kg) {
  const int first = blockIdx.x * 256;
  const bool isX = first < xg;
  const float* in        = isX ? x   : wt;
  unsigned char* outq    = isX ? xq  : wq;
  unsigned char* outsc   = isX ? xsc : wsc;
  const float gs         = isX ? ags[0] : wgs[0];
  const int rows         = isX ? Mrows : Nrows;
  const int base         = isX ? first : first - xg;
  const int g = base + threadIdx.x;
  const int r = g / kg, j = g - r * kg;

  float t[32];
  const float4* p4 = (const float4*)(in + (size_t)g * 32);
#pragma unroll
  for (int i = 0; i < 8; ++i) {
    float4 v4 = p4[i];
    t[4 * i + 0] = v4.x; t[4 * i + 1] = v4.y;
    t[4 * i + 2] = v4.z; t[4 * i + 3] = v4.w;
  }
#pragma unroll
  for (int s = 0; s < 5; ++s) {
    const int hh = 1 << s;
#pragma unroll
    for (int i = 0; i < 32; ++i) {
      if ((i & hh) == 0) {
        float a = t[i], b = t[i + hh];
        t[i] = a + b;
        t[i + hh] = a - b;
      }
    }
  }

  const float c = 0.17677669529663687f;  // 32^-0.5
  float v[32];
  float am = 0.0f;
#pragma unroll
  for (int i = 0; i < 32; ++i) {
    float vi = (t[i] * c) * gs;
    v[i] = vi;
    am = fmaxf(am, fabsf(vi));
  }

  float a6 = am / 6.0f;
  int ex;
  float mant = frexpf(a6, &ex);
  int e = (mant == 0.5f) ? ex - 1 : ex;  // exact ceil(log2(a6))
  if (e < -127) e = -127;
  if (e > 127) e = 127;
  float inv_s = ldexpf(1.0f, -e);

  unsigned int dw[4] = {0u, 0u, 0u, 0u};
#pragma unroll
  for (int i = 0; i < 32; ++i) {
    float u = v[i] * inv_s;
    float au = fabsf(u);
    int idx = (au > 0.25f) + (au > 0.75f) + (au > 1.25f) + (au > 1.75f)
            + (au > 2.5f) + (au > 3.5f) + (au > 5.0f);
    int code = idx | ((u < 0.0f) ? 8 : 0);
    dw[i >> 3] |= (unsigned)code << ((i & 7) * 4);
  }
  i32x4 packed;
  packed[0] = (int)dw[0]; packed[1] = (int)dw[1];
  packed[2] = (int)dw[2]; packed[3] = (int)dw[3];
  *(i32x4*)(outq + (size_t)r * ((size_t)kg * 16) + (size_t)j * 16) = packed;

  // scale byte: layout [step s(256k)][row][8B], byte p = h*4 + kk for block j0 = 2*kk + h
  int s = j >> 3, j0 = j & 7;
  int p = ((j0 & 1) << 2) | (j0 >> 1);
  if (kg == 128) {
    __shared__ unsigned char sl[256];  // [16 steps][2 rows][8B]
    sl[(s << 4) | ((r & 1) << 3) | p] = (unsigned char)(e + 127);
    __syncthreads();
    if (threadIdx.x < 64) {
      int si = threadIdx.x >> 2, wd = threadIdx.x & 3;
      unsigned int vv = *(const unsigned int*)&sl[(si << 4) | (wd << 2)];
      size_t r0 = (size_t)(base / 128);
      *(unsigned int*)(outsc + ((size_t)si * rows + r0) * 8 + (wd << 2)) = vv;
    }
  } else {
    outsc[((size_t)s * rows + r) * 8 + p] = (unsigned char)(e + 127);
  }
}

// ------------ 128x128 MX-FP4 GEMM, BK=256, half-K interleave, dbuf'd scale regs -------
// 4 waves (2M x 2N of 64x64), 2 blocks/CU. Frag regs split by k-half (kk01/kk23) =
// register double-buffer; scale regs saA/sbA (even tiles) and saB/sbB (odd tiles) so
// next-tile scale reads never clobber current-tile MFMA inputs (R15's bug). Loop
// unrolled by 2 tiles -> all reg indexing compile-time. Per tile t (buf p):
//  s1: lgkm0 -> reads kk23(t) [buf p] || 8 MFMA kk01(t)
//  s2: lgkm0 + barrier [ALL buf-p reads done] -> stage set(t+2)->buf[p] -> vm10 -> barrier
//  s3: reads kk01(t+1)+scales(next set) [buf p^1] || 8 MFMA kk23(t) (current set)
// Ledger: 10 VMEM/set; at VM10 queue = [set(t+1)^10, set(t+2)^10] -> drains set(t+1).

#define STAGE(mb, kt, hh, ldsHalf) do {                                              \
    const unsigned char* _s = (mb) + (size_t)((hh)*64 + (w << 3) + (l >> 3)) * KB2   \
                      + (size_t)(kt) * 128 + (size_t)csw * 16;                       \
    gload_lds16(_s, (unsigned char*)(ldsHalf) + (w << 10));                          \
    gload_lds16(_s + ((size_t)KB2 << 5), (unsigned char*)(ldsHalf) + (w << 10) + 4096); \
  } while (0)

#define STAGE_ASC(kt, bf) gload_lds4(AscG + ((size_t)(kt) * M + brow) * 8 + (tid << 2), \
                                     (unsigned char*)&asc[bf][0] + (w << 8))
#define STAGE_BSC(kt, bf) gload_lds4(BscG + ((size_t)(kt) * N + bcol) * 8 + (tid << 2), \
                                     (unsigned char*)&bsc[bf][0] + (w << 8))

// full tile set: 4 B-data + BSC + 4 A-data + ASC = 10 VMEM
#define STAGESET(kt, bf) do {                                                        \
    STAGE(Bb, kt, 0, &lds[bf][1][0]); STAGE(Bb, kt, 1, &lds[bf][1][8192]);           \
    STAGE_BSC(kt, bf);                                                               \
    STAGE(Ab, kt, 0, &lds[bf][0][0]); STAGE(Ab, kt, 1, &lds[bf][0][8192]);           \
    STAGE_ASC(kt, bf);                                                               \
  } while (0)

// half-1: kk = 0,1 + scale words into the GIVEN scale set (SA/SB)
#define READFRAGS_H1(bf, SA, SB) do {                                                \
    const unsigned char* _bb = &lds[bf][1][0];                                       \
    _Pragma("unroll")                                                                \
    for (int nt = 0; nt < 2; ++nt) {                                                 \
      int row = wn * 64 + nt * 32 + (l & 31);                                        \
      int xr = row & 7;                                                              \
      _Pragma("unroll")                                                              \
      for (int kk = 0; kk < 2; ++kk)                                                 \
        *(i32x4*)&bf8[nt][kk] = *(const i32x4*)(_bb + row * 128 + (((kk * 2 + h) ^ xr) << 4)); \
      SB[nt] = *(const int*)((const unsigned char*)&bsc[bf][0] + row * 8 + h * 4);   \
    }                                                                                \
    const unsigned char* _ab = &lds[bf][0][0];                                       \
    _Pragma("unroll")                                                                \
    for (int mt = 0; mt < 2; ++mt) {                                                 \
      int row = wm * 64 + mt * 32 + (l & 31);                                        \
      int xr = row & 7;                                                              \
      _Pragma("unroll")                                                              \
      for (int kk = 0; kk < 2; ++kk)                                                 \
        *(i32x4*)&af8[mt][kk] = *(const i32x4*)(_ab + row * 128 + (((kk * 2 + h) ^ xr) << 4)); \
      SA[mt] = *(const int*)((const unsigned char*)&asc[bf][0] + row * 8 + h * 4);   \
    } } while (0)

// half-2: kk = 2,3 (data only; scales already resident in the current set)
#define READFRAGS_H2(bf) do {                                                        \
    const unsigned char* _bb = &lds[bf][1][0];                                       \
    _Pragma("unroll")                                                                \
    for (int nt = 0; nt < 2; ++nt) {                                                 \
      int row = wn * 64 + nt * 32 + (l & 31);                                        \
      int xr = row & 7;                                                              \
      _Pragma("unroll")                                                              \
      for (int kk = 2; kk < 4; ++kk)                                                 \
        *(i32x4*)&bf8[nt][kk] = *(const i32x4*)(_bb + row * 128 + (((kk * 2 + h) ^ xr) << 4)); \
    }                                                                                \
    const unsigned char* _ab = &lds[bf][0][0];                                       \
    _Pragma("unroll")                                                                \
    for (int mt = 0; mt < 2; ++mt) {                                                 \
      int row = wm * 64 + mt * 32 + (l & 31);                                        \
      int xr = row & 7;                                                              \
      _Pragma("unroll")                                                              \
      for (int kk = 2; kk < 4; ++kk)                                                 \
        *(i32x4*)&af8[mt][kk] = *(const i32x4*)(_ab + row * 128 + (((kk * 2 + h) ^ xr) << 4)); \
    } } while (0)

#define MF1(mt, nt, kk, SA, SB)                                                      \
  acc[mt][nt] = __builtin_amdgcn_mfma_scale_f32_32x32x64_f8f6f4(                     \
      af8[mt][kk], bf8[nt][kk], acc[mt][nt], 4, 4, kk, SA[mt], kk, SB[nt]);

#define MFMAQ_H1(SA, SB) do {                                                        \
    __builtin_amdgcn_s_setprio(1);                                                   \
    MF1(0, 0, 0, SA, SB) MF1(0, 1, 0, SA, SB) MF1(1, 0, 0, SA, SB) MF1(1, 1, 0, SA, SB) \
    MF1(0, 0, 1, SA, SB) MF1(0, 1, 1, SA, SB) MF1(1, 0, 1, SA, SB) MF1(1, 1, 1, SA, SB) \
    __builtin_amdgcn_s_setprio(0);                                                   \
  } while (0)

#define MFMAQ_H2(SA, SB) do {                                                        \
    __builtin_amdgcn_s_setprio(1);                                                   \
    MF1(0, 0, 2, SA, SB) MF1(0, 1, 2, SA, SB) MF1(1, 0, 2, SA, SB) MF1(1, 1, 2, SA, SB) \
    MF1(0, 0, 3, SA, SB) MF1(0, 1, 3, SA, SB) MF1(1, 0, 3, SA, SB) MF1(1, 1, 3, SA, SB) \
    __builtin_amdgcn_s_setprio(0);                                                   \
  } while (0)

#define LGKM0() do {                                                                 \
    asm volatile("s_waitcnt lgkmcnt(0)" ::: "memory");                               \
    __builtin_amdgcn_sched_barrier(0);                                               \
  } while (0)

#define ENDP() __builtin_amdgcn_s_barrier()
#define VM10() asm volatile("s_waitcnt vmcnt(10)" ::: "memory")

// one tile: s1/s2/s3 (BF = this tile's buf, OBF = other buf; CURA/CURB = this tile's
// scale regs, NXTA/NXTB = next tile's)
#define TILE(BF, OBF, tstage, CURA, CURB, NXTA, NXTB) do {                           \
    LGKM0();                                                                         \
    READFRAGS_H2(BF);                                                                \
    MFMAQ_H1(CURA, CURB);                                                            \
    LGKM0();                                                                         \
    __builtin_amdgcn_s_barrier();                                                    \
    STAGESET(tstage, BF);                                                            \
    __builtin_amdgcn_sched_barrier(0);                                               \
    VM10();                                                                          \
    ENDP();                                                                          \
    READFRAGS_H1(OBF, NXTA, NXTB);                                                   \
    MFMAQ_H2(CURA, CURB);                                                            \
  } while (0)

__global__ __launch_bounds__(256, 2) void gemm128_fp4(const unsigned char* __restrict__ Aq,
                                                      const unsigned char* __restrict__ Bq,
                                                      const unsigned char* __restrict__ AscG,
                                                      const unsigned char* __restrict__ BscG,
                                                      float* __restrict__ C,
                                                      const float* __restrict__ bias,
                                                      const float* __restrict__ gsx,
                                                      const float* __restrict__ gsw,
                                                      int M, int N, int K) {
  __shared__ __align__(16) unsigned char lds[2][2][16384];  // [buf][A/B][128 rows x 128B]
  __shared__ __align__(16) unsigned char asc[2][1024];      // [buf][128 rows x 8B]
  __shared__ __align__(16) unsigned char bsc[2][1024];

  const int tid = threadIdx.x;
  const int w = tid >> 6, l = tid & 63;
  const int wm = w >> 1, wn = w & 1;
  const int h = l >> 5;
  const int csw = (l & 7) ^ (l >> 3);  // inverse-swizzled source chunk (row&7 == l>>3)
  const int KB2 = K >> 1;              // bytes per row

  // T1 + L2 supertiling (proven: FETCH 148->70MB): XCD band + 8x8 supertiles.
  const int ntn = N >> 7;
  const int nwg = gridDim.x;
  int r_t, c_t;
  {
    int bid = blockIdx.x;
    if ((nwg & 7) == 0) {
      int x = bid & 7, o = bid >> 3, cpx = nwg >> 3;
      int rpx = cpx / ntn;
      if ((ntn & 7) == 0 && rpx > 0 && (cpx % ntn) == 0) {
        int g8 = o & 7, rr = (o >> 3) % rpx, ss = o / (8 * rpx);
        r_t = x * rpx + rr;
        c_t = ss * 8 + g8;
      } else {
        int lin = x * cpx + o;
        r_t = lin / ntn; c_t = lin % ntn;
      }
    } else {
      r_t = bid / ntn; c_t = bid % ntn;
    }
  }
  const size_t brow = (size_t)r_t * 128;
  const size_t bcol = (size_t)c_t * 128;

  const unsigned char* Ab = Aq + brow * (size_t)KB2;
  const unsigned char* Bb = Bq + bcol * (size_t)KB2;

  f32x16 acc[2][2];
#pragma unroll
  for (int m = 0; m < 2; ++m)
#pragma unroll
    for (int n = 0; n < 2; ++n)
#pragma unroll
      for (int r = 0; r < 16; ++r) acc[m][n][r] = 0.0f;

  // Persistent MFMA operand tuples (hi half zeroed once; ds_reads land in lo half).
  i32x8 af8[2][4], bf8[2][4];
#pragma unroll
  for (int mt = 0; mt < 2; ++mt)
#pragma unroll
    for (int kk = 0; kk < 4; ++kk) {
#pragma unroll
      for (int q = 0; q < 8; ++q) { af8[mt][kk][q] = 0; bf8[mt][kk][q] = 0; }
    }
  // Double-buffered scale regs: A-set for even tiles, B-set for odd tiles.
  int saA[2], sbA[2], saB[2], sbB[2];

  const int nkt = K / 256;       // 16 tiles (even); scale step index == tile index

  // Prologue: set(0)->buf0, set(1)->buf1; VM10 drains set0; prime kk01(0)+scalesA.
  STAGESET(0, 0);
  STAGESET(1, 1);
  VM10();
  __builtin_amdgcn_s_barrier();
  READFRAGS_H1(0, saA, sbA);

  for (int s = 0; s < nkt / 2; ++s) {
    const int t = 2 * s;
    const int t2 = (t + 2 < nkt) ? t + 2 : nkt - 1;  // tail: stages a buffer never read again
    const int t3 = (t + 3 < nkt) ? t + 3 : nkt - 1;

    // even tile t (buf0, scales A; preloads tile t+1's kk01 + scales B)
    TILE(0, 1, t2, saA, sbA, saB, sbB);
    // odd tile t+1 (buf1, scales B; preloads tile t+2's kk01 + scales A)
    TILE(1, 0, t3, saB, sbB, saA, sbA);
  }

  const float inv = 1.0f / (gsx[0] * gsw[0]);
#pragma unroll
  for (int nt = 0; nt < 2; ++nt) {
    const int col = (int)bcol + wn * 64 + nt * 32 + (l & 31);
    const float bv = bias[col];
#pragma unroll
    for (int mt = 0; mt < 2; ++mt) {
      const size_t rbase = brow + (size_t)(wm * 64 + mt * 32 + 4 * h);
#pragma unroll
      for (int r = 0; r < 16; ++r) {
        const size_t row = rbase + (r & 3) + 8 * (r >> 2);
        C[row * (size_t)N + col] = acc[mt][nt][r] * inv + bv;
      }
    }
  }
}

extern "C" void kernel_launch(void* const* d_in, const int* in_sizes, int n_in,
                              void* d_out, int out_size, void* d_ws, size_t ws_size,
                              hipStream_t stream) {
  const float* x    = (const float*)d_in[0];
  const float* wgt  = (const float*)d_in[1];
  const float* bias = (const float*)d_in[2];
  const float* wgs  = (const float*)d_in[4];
  const float* ags  = (const float*)d_in[5];

  const int N = in_sizes[2];            // 4096
  const int K = in_sizes[1] / N;        // 4096
  const int M = in_sizes[0] / K;        // 8192
  const int kg = K / 32;                // 128

  unsigned char* aq  = (unsigned char*)d_ws;
  unsigned char* bq  = aq + (size_t)M * (K / 2);
  unsigned char* asc = bq + (size_t)N * (K / 2);
  unsigned char* bsc = asc + (size_t)M * kg;

  const int xg = in_sizes[0] / 32;
  const int wg = in_sizes[1] / 32;
  quant_fused<<<dim3((xg + wg) / 256), dim3(256), 0, stream>>>(
      x, wgt, aq, asc, bq, bsc, ags, wgs, xg, M, N, kg);

  dim3 grid((M / 128) * (N / 128));
  gemm128_fp4<<<grid, dim3(256), 0, stream>>>(aq, bq, asc, bsc, (float*)d_out, bias,
                                              ags, wgs, M, N, K);
}